// Round 5
// baseline (844.418 us; speedup 1.0000x reference)
//
#include <hip/hip_runtime.h>
#include <hip/hip_bf16.h>
#include <math.h>

#define FDIM 512
#define NEXP 4
#define HDIM 256
#define ADIM 32
#define BM   32
#define NTHR 512

typedef __attribute__((ext_vector_type(8))) short frag8;   // 8 bf16 (4 VGPR)
typedef __attribute__((ext_vector_type(4))) float f32x4;

// ws layout (ushort elements)
#define W1T_OFF 0                        // [4][256][512]  n-major
#define W2T_OFF (4*256*512)              // [4][32][256]   a-major
#define WGT_OFF (W2T_OFF + 4*32*256)     // [16][512]      rows 4..15 zero

__device__ inline ushort f2bf(float x) {
    union { float f; unsigned u; } v; v.f = x;
    unsigned r = v.u + 0x7FFFu + ((v.u >> 16) & 1u);   // RNE
    return (ushort)(r >> 16);
}

__device__ inline frag8 pack8(f32x4 a, f32x4 b) {
    frag8 r;
    r[0] = (short)f2bf(a[0]); r[1] = (short)f2bf(a[1]);
    r[2] = (short)f2bf(a[2]); r[3] = (short)f2bf(a[3]);
    r[4] = (short)f2bf(b[0]); r[5] = (short)f2bf(b[1]);
    r[6] = (short)f2bf(b[2]); r[7] = (short)f2bf(b[3]);
    return r;
}

// ---------------- prep: fp32 weights -> transposed bf16 in ws ----------------
__global__ __launch_bounds__(256) void moe_prep(const float* __restrict__ Wg,
                                                const float* __restrict__ W1,
                                                const float* __restrict__ W2,
                                                ushort* __restrict__ ws) {
    const int b = blockIdx.x, t = threadIdx.x;
    if (b < 64) {
        // W1[e][k][n] -> W1t[e][n][k]; 65536 octets over 16384 threads
        #pragma unroll
        for (int it = 0; it < 4; ++it) {
            int oct = (b * 256 + t) + it * 16384;
            int n = oct & 255, k8 = (oct >> 8) & 63, e = oct >> 14;
            f32x4 v0, v1;
            #pragma unroll
            for (int j = 0; j < 4; ++j) v0[j] = W1[(e*512 + k8*8 + j)*256 + n];
            #pragma unroll
            for (int j = 0; j < 4; ++j) v1[j] = W1[(e*512 + k8*8 + 4 + j)*256 + n];
            *(frag8*)(ws + W1T_OFF + (e*HDIM + n)*FDIM + k8*8) = pack8(v0, v1);
        }
    } else if (b < 80) {
        // W2[e][n][a] -> W2t[e][a][n]; 4096 octets
        int oct = (b - 64) * 256 + t;
        int a = oct & 31, n8 = (oct >> 5) & 31, e = oct >> 10;
        f32x4 v0, v1;
        #pragma unroll
        for (int j = 0; j < 4; ++j) v0[j] = W2[(e*HDIM + n8*8 + j)*ADIM + a];
        #pragma unroll
        for (int j = 0; j < 4; ++j) v1[j] = W2[(e*HDIM + n8*8 + 4 + j)*ADIM + a];
        *(frag8*)(ws + W2T_OFF + (e*ADIM + a)*HDIM + n8*8) = pack8(v0, v1);
    } else {
        // Wg[k][c] -> Wgt[c][k], c padded to 16 with zeros; 1024 octets
        int oct = (b - 80) * 256 + t;
        int k8 = oct & 63, c = oct >> 6;
        f32x4 v0 = {0,0,0,0}, v1 = {0,0,0,0};
        if (c < NEXP) {
            #pragma unroll
            for (int j = 0; j < 4; ++j) v0[j] = Wg[(k8*8 + j)*NEXP + c];
            #pragma unroll
            for (int j = 0; j < 4; ++j) v1[j] = Wg[(k8*8 + 4 + j)*NEXP + c];
        }
        *(frag8*)(ws + WGT_OFF + c*FDIM + k8*8) = pack8(v0, v1);
    }
}

// ---------------- main fused kernel ----------------
// BM=32: LDS = fbuf 32KB ([32][512] bf16 swizzled) + hbuf 32KB ([2][32][256] bf16
// swizzled) + gate 512B = 64.5KB -> 2 blocks/CU (16 waves/CU, 4 waves/SIMD).
// Rationale R3: 1-block/CU config measured latency-bound (MfmaUtil 13.7, VALU 12.5,
// HBM 5%, occ 24%) — cross-block overlap is the missing latency hider.
__global__ __launch_bounds__(NTHR, 4) void moe_main(
        const float* __restrict__ feat, const float* __restrict__ bg,
        const float* __restrict__ b1,  const float* __restrict__ b2,
        const ushort* __restrict__ ws, float* __restrict__ out) {
    __shared__ __attribute__((aligned(16))) unsigned char smem[32768 + 32768 + 512];
    unsigned char* fbuf = smem;
    unsigned char* hbuf = smem + 32768;
    float* gate = (float*)(smem + 65536);

    const int tid = threadIdx.x;
    const int lane = tid & 63;
    const int wave = tid >> 6;        // 0..7
    const int l15 = lane & 15;
    const int lg  = lane >> 4;        // 0..3
    const int row0 = blockIdx.x * BM;
    const ushort* w1t = ws + W1T_OFF;
    const ushort* w2t = ws + W2T_OFF;
    const ushort* wgt = ws + WGT_OFF;

    // ---- stage features fp32 -> bf16 LDS (swizzle: byte ^= (row&7)<<4) ----
    {
        const float* fsrc = feat + (size_t)row0 * FDIM;
        #pragma unroll
        for (int it = 0; it < 4; ++it) {
            int c = tid + it * NTHR;          // 16B-chunk id, 0..2047
            int r = c >> 6, c8 = c & 63;
            const float* p = fsrc + r * FDIM + c8 * 8;
            f32x4 v0 = *(const f32x4*)p;
            f32x4 v1 = *(const f32x4*)(p + 4);
            *(frag8*)(fbuf + r * 1024 + ((c8 * 16) ^ ((r & 7) << 4))) = pack8(v0, v1);
        }
    }
    __syncthreads();

    // ---- gate logits via MFMA (waves 0..1, row-tile = wave) ----
    if (wave < 2) {
        const int rt = wave;
        const int arow = rt * 16 + l15;
        const int aswz = (arow & 7) << 4;
        f32x4 acc = {0.f, 0.f, 0.f, 0.f};
        #pragma unroll
        for (int s = 0; s < 16; ++s) {
            int k8 = s * 4 + lg;
            frag8 a = *(const frag8*)(fbuf + arow * 1024 + ((k8 * 16) ^ aswz));
            frag8 bb = *(const frag8*)(wgt + l15 * FDIM + k8 * 8);
            acc = __builtin_amdgcn_mfma_f32_16x16x32_bf16(a, bb, acc, 0, 0, 0);
        }
        if (l15 < NEXP) {
            float bgv = bg[l15];
            #pragma unroll
            for (int r = 0; r < 4; ++r)
                gate[(rt * 16 + lg * 4 + r) * 4 + l15] = acc[r] + bgv;
        }
    }
    __syncthreads();
    if (tid < BM) {   // softmax per row
        f32x4 g = *(const f32x4*)(gate + tid * 4);
        float m = fmaxf(fmaxf(g[0], g[1]), fmaxf(g[2], g[3]));
        float e0 = expf(g[0]-m), e1 = expf(g[1]-m), e2 = expf(g[2]-m), e3 = expf(g[3]-m);
        float inv = 1.f / (e0 + e1 + e2 + e3);
        f32x4 r = { e0*inv, e1*inv, e2*inv, e3*inv };
        *(f32x4*)(gate + tid * 4) = r;
    }
    __syncthreads();

    // GEMM2 tile assignment (waves 0..3): rt2 = wave>>1 (0..1), ct2 = wave&1
    const int rt2 = wave >> 1, ct2 = wave & 1;
    f32x4 gv[4];
    f32x4 act = {0.f, 0.f, 0.f, 0.f};
    if (wave < 4) {
        #pragma unroll
        for (int r = 0; r < 4; ++r)
            gv[r] = *(const f32x4*)(gate + (rt2 * 16 + lg * 4 + r) * 4);
    }

    // ---- expert-pair loop ----
    #pragma unroll
    for (int p = 0; p < 2; ++p) {
        f32x4 acc[2][2][2];   // [eo][rt][ct]
        #pragma unroll
        for (int eo = 0; eo < 2; ++eo)
            #pragma unroll
            for (int rt = 0; rt < 2; ++rt)
                #pragma unroll
                for (int ct = 0; ct < 2; ++ct)
                    acc[eo][rt][ct] = (f32x4){0.f, 0.f, 0.f, 0.f};

        // GEMM1: [32 x 512] x [512 x 32cols-per-wave] for 2 experts
        #pragma unroll 4
        for (int s = 0; s < 16; ++s) {
            int k8 = s * 4 + lg;
            frag8 a[2];
            #pragma unroll
            for (int rt = 0; rt < 2; ++rt) {
                int arow = rt * 16 + l15;
                a[rt] = *(const frag8*)(fbuf + arow * 1024 + ((k8 * 16) ^ ((arow & 7) << 4)));
            }
            frag8 bb[2][2];
            #pragma unroll
            for (int eo = 0; eo < 2; ++eo)
                #pragma unroll
                for (int ct = 0; ct < 2; ++ct) {
                    int col = (wave * 2 + ct) * 16 + l15;
                    bb[eo][ct] = *(const frag8*)(w1t + ((2*p + eo) * HDIM + col) * FDIM + k8 * 8);
                }
            #pragma unroll
            for (int eo = 0; eo < 2; ++eo)
                #pragma unroll
                for (int rt = 0; rt < 2; ++rt)
                    #pragma unroll
                    for (int ct = 0; ct < 2; ++ct)
                        acc[eo][rt][ct] = __builtin_amdgcn_mfma_f32_16x16x32_bf16(
                            a[rt], bb[eo][ct], acc[eo][rt][ct], 0, 0, 0);
        }

        __syncthreads();   // previous pair's GEMM2 reads of hbuf complete
        // h = relu(acc + b1) -> bf16 -> hbuf (swizzled)
        #pragma unroll
        for (int eo = 0; eo < 2; ++eo) {
            int e = 2 * p + eo;
            #pragma unroll
            for (int ct = 0; ct < 2; ++ct) {
                int col = (wave * 2 + ct) * 16 + l15;
                float bias = b1[e * HDIM + col];
                #pragma unroll
                for (int rt = 0; rt < 2; ++rt)
                    #pragma unroll
                    for (int r = 0; r < 4; ++r) {
                        int row = rt * 16 + lg * 4 + r;
                        float v = fmaxf(acc[eo][rt][ct][r] + bias, 0.f);
                        *(ushort*)(hbuf + eo * 16384 + row * 512 +
                                   ((2 * col) ^ ((row & 7) << 4))) = f2bf(v);
                    }
            }
        }
        __syncthreads();

        // GEMM2: out[32x32] per expert, gate-weighted accumulate (waves 0..3)
        if (wave < 4) {
            #pragma unroll
            for (int eo = 0; eo < 2; ++eo) {
                const int arow = rt2 * 16 + l15;
                const int aswz = (arow & 7) << 4;
                const unsigned char* hb = hbuf + eo * 16384;
                f32x4 o = {0.f, 0.f, 0.f, 0.f};
                #pragma unroll
                for (int s = 0; s < 8; ++s) {
                    int k8 = s * 4 + lg;
                    frag8 a = *(const frag8*)(hb + arow * 512 + ((k8 * 16) ^ aswz));
                    frag8 bb = *(const frag8*)(w2t + ((2*p + eo) * ADIM + ct2 * 16 + l15) * HDIM + k8 * 8);
                    o = __builtin_amdgcn_mfma_f32_16x16x32_bf16(a, bb, o, 0, 0, 0);
                }
                #pragma unroll
                for (int r = 0; r < 4; ++r)
                    act[r] += gv[r][2*p + eo] * o[r];
            }
        }
    }

    // ---- epilogue: + sum_e gate_e * b2[e] (softmax sums to 1), store ----
    if (wave < 4) {
        int col = ct2 * 16 + l15;
        float b2v0 = b2[0*ADIM + col], b2v1 = b2[1*ADIM + col];
        float b2v2 = b2[2*ADIM + col], b2v3 = b2[3*ADIM + col];
        #pragma unroll
        for (int r = 0; r < 4; ++r) {
            int row = row0 + rt2 * 16 + lg * 4 + r;
            float bs = gv[r][0]*b2v0 + gv[r][1]*b2v1 + gv[r][2]*b2v2 + gv[r][3]*b2v3;
            out[(size_t)row * ADIM + col] = act[r] + bs;
        }
    }
}

extern "C" void kernel_launch(void* const* d_in, const int* in_sizes, int n_in,
                              void* d_out, int out_size, void* d_ws, size_t ws_size,
                              hipStream_t stream) {
    const float* feat = (const float*)d_in[0];
    const float* Wg   = (const float*)d_in[1];
    const float* bg   = (const float*)d_in[2];
    const float* W1   = (const float*)d_in[3];
    const float* b1   = (const float*)d_in[4];
    const float* W2   = (const float*)d_in[5];
    const float* b2   = (const float*)d_in[6];
    float* out = (float*)d_out;
    ushort* ws = (ushort*)d_ws;

    moe_prep<<<84, 256, 0, stream>>>(Wg, W1, W2, ws);
    const int nblk = (131072 + BM - 1) / BM;   // 4096
    moe_main<<<nblk, NTHR, 0, stream>>>(feat, bg, b1, b2, ws, out);
}

// Round 6
// 694.593 us; speedup vs baseline: 1.2157x; 1.2157x over previous
//
#include <hip/hip_runtime.h>
#include <hip/hip_bf16.h>
#include <math.h>

#define FDIM 512
#define NEXP 4
#define HDIM 256
#define ADIM 32
#define BM   128
#define NTHR 512

typedef __attribute__((ext_vector_type(8))) short frag8;   // 8 bf16 (4 VGPR)
typedef __attribute__((ext_vector_type(4))) float f32x4;

// ws layout (ushort elements)
#define W1T_OFF 0                        // [4][256][512]  n-major (col stride 1KB)
#define W2T_OFF (4*256*512)              // [4][32][256]   a-major
#define WGT_OFF (W2T_OFF + 4*32*256)     // [16][512]      rows 4..15 zero

__device__ inline ushort f2bf(float x) {
    union { float f; unsigned u; } v; v.f = x;
    unsigned r = v.u + 0x7FFFu + ((v.u >> 16) & 1u);   // RNE
    return (ushort)(r >> 16);
}

__device__ inline frag8 pack8(f32x4 a, f32x4 b) {
    frag8 r;
    r[0] = (short)f2bf(a[0]); r[1] = (short)f2bf(a[1]);
    r[2] = (short)f2bf(a[2]); r[3] = (short)f2bf(a[3]);
    r[4] = (short)f2bf(b[0]); r[5] = (short)f2bf(b[1]);
    r[6] = (short)f2bf(b[2]); r[7] = (short)f2bf(b[3]);
    return r;
}

// async global->LDS, 16B per lane; LDS dest = wave-uniform base + lane*16
__device__ __forceinline__ void gl16(const void* g, void* l) {
    __builtin_amdgcn_global_load_lds(
        (const __attribute__((address_space(1))) unsigned int*)g,
        (__attribute__((address_space(3))) unsigned int*)l, 16, 0, 0);
}

// ---------------- prep: fp32 weights -> transposed bf16 in ws ----------------
__global__ __launch_bounds__(256) void moe_prep(const float* __restrict__ Wg,
                                                const float* __restrict__ W1,
                                                const float* __restrict__ W2,
                                                ushort* __restrict__ ws) {
    const int b = blockIdx.x, t = threadIdx.x;
    if (b < 64) {
        // W1[e][k][n] -> W1t[e][n][k]; 65536 octets over 16384 threads
        #pragma unroll
        for (int it = 0; it < 4; ++it) {
            int oct = (b * 256 + t) + it * 16384;
            int n = oct & 255, k8 = (oct >> 8) & 63, e = oct >> 14;
            f32x4 v0, v1;
            #pragma unroll
            for (int j = 0; j < 4; ++j) v0[j] = W1[(e*512 + k8*8 + j)*256 + n];
            #pragma unroll
            for (int j = 0; j < 4; ++j) v1[j] = W1[(e*512 + k8*8 + 4 + j)*256 + n];
            *(frag8*)(ws + W1T_OFF + (e*HDIM + n)*FDIM + k8*8) = pack8(v0, v1);
        }
    } else if (b < 80) {
        // W2[e][n][a] -> W2t[e][a][n]; 4096 octets
        int oct = (b - 64) * 256 + t;
        int a = oct & 31, n8 = (oct >> 5) & 31, e = oct >> 10;
        f32x4 v0, v1;
        #pragma unroll
        for (int j = 0; j < 4; ++j) v0[j] = W2[(e*HDIM + n8*8 + j)*ADIM + a];
        #pragma unroll
        for (int j = 0; j < 4; ++j) v1[j] = W2[(e*HDIM + n8*8 + 4 + j)*ADIM + a];
        *(frag8*)(ws + W2T_OFF + (e*ADIM + a)*HDIM + n8*8) = pack8(v0, v1);
    } else {
        // Wg[k][c] -> Wgt[c][k], c padded to 16 with zeros; 1024 octets
        int oct = (b - 80) * 256 + t;
        int k8 = oct & 63, c = oct >> 6;
        f32x4 v0 = {0,0,0,0}, v1 = {0,0,0,0};
        if (c < NEXP) {
            #pragma unroll
            for (int j = 0; j < 4; ++j) v0[j] = Wg[(k8*8 + j)*NEXP + c];
            #pragma unroll
            for (int j = 0; j < 4; ++j) v1[j] = Wg[(k8*8 + 4 + j)*NEXP + c];
        }
        *(frag8*)(ws + WGT_OFF + c*FDIM + k8*8) = pack8(v0, v1);
    }
}

// ---------------- main fused kernel (v3: A-in-regs, B via LDS dbuf) ----------------
// R5 post-mortem: occupancy was not the limiter (24->46% made dur worse); the stall
// is scattered global weight loads in the MFMA inner loop. v3: features loaded ONCE
// to registers (reused for all 4 experts), W1 panels staged to LDS double-buffered
// via global_load_lds with inverse-swizzled source (rule 21), swizzled ds_read_b128
// B-frags (T2, verified 8-cyc optimal). LDS 146KB -> 1 block/CU, 8 waves.
__global__ __launch_bounds__(NTHR, 2) void moe_main(
        const float* __restrict__ feat, const float* __restrict__ bg,
        const float* __restrict__ b1,  const float* __restrict__ b2,
        const ushort* __restrict__ ws, float* __restrict__ out) {
    __shared__ __attribute__((aligned(16))) unsigned char smem[65536 + 65536 + 16384 + 2048];
    unsigned char* bufA = smem;                    // 64KB: W1 chunk / H transpose
    unsigned char* bufB = smem + 65536;            // 64KB: W1 chunk
    unsigned char* wgtb = smem + 131072;           // 16KB: gate weights
    float*         wgate = (float*)(smem + 147456);// 8 waves x 16 rows x 4 experts

    const int tid = threadIdx.x;
    const int lane = tid & 63;
    const int wave = tid >> 6;        // 0..7
    const int l15 = lane & 15;
    const int lg  = lane >> 4;        // 0..3
    const int row0 = blockIdx.x * BM;
    const int wrow = row0 + wave * 16;            // this wave's 16 rows
    const ushort* w2t = ws + W2T_OFF;
    const char* w1b = (const char*)(ws + W1T_OFF);
    const char* wgb = (const char*)(ws + WGT_OFF);

    // per-thread staging source offsets (inverse-swizzled so linear LDS + XOR read works)
    int sOff[8];
    #pragma unroll
    for (int j = 0; j < 8; ++j) {
        int slot = j * 512 + tid;                 // 0..4095 (16B slots of 64KB chunk)
        int col  = slot >> 4;                     // 0..255, LDS col stride 256B
        int kkp  = ((slot & 15) * 16) ^ ((col & 7) << 4);
        sOff[j]  = col * 1024 + kkp;              // bytes within expert's W1t block
    }
    int gOff[2];
    #pragma unroll
    for (int j = 0; j < 2; ++j) {
        int slot = j * 512 + tid;                 // 0..1023 (16B slots of 16KB)
        int col  = slot >> 6;                     // 0..15, LDS col stride 1024B
        int off  = (slot & 63) * 16;
        gOff[j]  = col * 1024 + (off ^ ((col & 7) << 4));
    }

    // issue gate-weight stage + expert0 chunk0 stage (async, drained at barrier)
    #pragma unroll
    for (int j = 0; j < 2; ++j)
        gl16(wgb + gOff[j], wgtb + j * 8192 + wave * 1024);
    #pragma unroll
    for (int j = 0; j < 8; ++j)
        gl16(w1b + sOff[j], bufA + j * 8192 + wave * 1024);

    // features -> A-fragments in registers (each wave owns 16 rows; read HBM once)
    frag8 afrag[16];
    const float* fp = feat + (size_t)(wrow + l15) * FDIM + lg * 8;
    #pragma unroll
    for (int g4 = 0; g4 < 4; ++g4) {
        f32x4 t0[4], t1[4];
        #pragma unroll
        for (int s = 0; s < 4; ++s) {
            const float* p = fp + (g4 * 4 + s) * 32;
            t0[s] = *(const f32x4*)p;
            t1[s] = *(const f32x4*)(p + 4);
        }
        #pragma unroll
        for (int s = 0; s < 4; ++s) afrag[g4 * 4 + s] = pack8(t0[s], t1[s]);
    }

    __syncthreads();   // wgtb + chunk0 staged

    // ---- gate: 16 MFMA vs staged Wgt, then 4-lane-group softmax ----
    {
        f32x4 ga = {0.f, 0.f, 0.f, 0.f};
        #pragma unroll
        for (int s = 0; s < 16; ++s) {
            frag8 bb = *(const frag8*)(wgtb + l15 * 1024 + ((s * 64 + lg * 16) ^ ((l15 & 7) << 4)));
            ga = __builtin_amdgcn_mfma_f32_16x16x32_bf16(afrag[s], bb, ga, 0, 0, 0);
        }
        float bgv = bg[l15 & 3];
        #pragma unroll
        for (int r = 0; r < 4; ++r) {
            float v = ga[r] + bgv;                 // logit (lanes l15<4 meaningful)
            float m = fmaxf(v, __shfl_xor(v, 1));
            m = fmaxf(m, __shfl_xor(m, 2));
            float eV = expf(v - m);
            float sV = eV + __shfl_xor(eV, 1);
            sV += __shfl_xor(sV, 2);
            float g = eV / sV;
            if (l15 < NEXP) wgate[wave * 64 + (lg * 4 + r) * 4 + l15] = g;
        }
    }

    f32x4 act[2];
    act[0] = (f32x4){0.f, 0.f, 0.f, 0.f};
    act[1] = (f32x4){0.f, 0.f, 0.f, 0.f};

    // ---- expert loop (rolled; all per-lane array indices compile-time) ----
    for (int e = 0; e < NEXP; ++e) {
        f32x4 acc1[16];
        #pragma unroll
        for (int ct = 0; ct < 16; ++ct) acc1[ct] = (f32x4){0.f, 0.f, 0.f, 0.f};

        const char* wbase = w1b + e * 262144;     // expert's W1t block (256KB)

        #pragma unroll
        for (int c = 0; c < 4; ++c) {             // 4 k-chunks of 128
            if (c < 3) {                          // stage next chunk into other buf
                unsigned char* dst = ((c + 1) & 1) ? bufB : bufA;
                #pragma unroll
                for (int j = 0; j < 8; ++j)
                    gl16(wbase + (c + 1) * 256 + sOff[j], dst + j * 8192 + wave * 1024);
            }
            __syncthreads();                      // chunk c ready
            unsigned char* src = (c & 1) ? bufB : bufA;
            #pragma unroll
            for (int s = 0; s < 4; ++s) {
                #pragma unroll
                for (int ct = 0; ct < 16; ++ct) {
                    frag8 bb = *(const frag8*)(src + (ct * 16 + l15) * 256 +
                                               ((s * 64 + lg * 16) ^ ((l15 & 7) << 4)));
                    acc1[ct] = __builtin_amdgcn_mfma_f32_16x16x32_bf16(
                        afrag[c * 4 + s], bb, acc1[ct], 0, 0, 0);
                }
            }
            if (c < 3) __syncthreads();           // compute done before buf re-staged
        }

        // ---- H = relu(acc1+b1) -> per-wave LDS region in bufA (swizzled), then GEMM2 ----
        unsigned char* hb = bufA + wave * 8192;   // [16 rows][256 cols] bf16, row stride 512B
        #pragma unroll
        for (int ct = 0; ct < 16; ++ct) {
            float b1v = b1[e * HDIM + ct * 16 + l15];
            #pragma unroll
            for (int r = 0; r < 4; ++r) {
                int row = lg * 4 + r;
                float v = fmaxf(acc1[ct][r] + b1v, 0.f);
                *(ushort*)(hb + row * 512 + (((ct * 16 + l15) * 2) ^ ((row & 7) << 4))) = f2bf(v);
            }
        }
        asm volatile("s_waitcnt lgkmcnt(0)" ::: "memory");   // own H writes visible
        __builtin_amdgcn_sched_barrier(0);                   // rule 18

        f32x4 acc2[2];
        acc2[0] = (f32x4){0.f, 0.f, 0.f, 0.f};
        acc2[1] = (f32x4){0.f, 0.f, 0.f, 0.f};
        #pragma unroll
        for (int s2 = 0; s2 < 8; ++s2) {
            frag8 ha = *(const frag8*)(hb + l15 * 512 + ((s2 * 64 + lg * 16) ^ ((l15 & 7) << 4)));
            #pragma unroll
            for (int ct2 = 0; ct2 < 2; ++ct2) {
                frag8 bb = *(const frag8*)(w2t + (e * ADIM + ct2 * 16 + l15) * HDIM + (s2 * 4 + lg) * 8);
                acc2[ct2] = __builtin_amdgcn_mfma_f32_16x16x32_bf16(ha, bb, acc2[ct2], 0, 0, 0);
            }
        }
        // gate-weighted accumulate, b2 folded per expert
        #pragma unroll
        for (int ct2 = 0; ct2 < 2; ++ct2) {
            float b2v = b2[e * ADIM + ct2 * 16 + l15];
            #pragma unroll
            for (int r = 0; r < 4; ++r) {
                float g = wgate[wave * 64 + (lg * 4 + r) * 4 + e];
                act[ct2][r] += g * (acc2[ct2][r] + b2v);
            }
        }

        if (e < 3) {     // all waves done reading H(bufA) -> stage next expert's chunk0
            __syncthreads();
            const char* nb = w1b + (e + 1) * 262144;
            #pragma unroll
            for (int j = 0; j < 8; ++j)
                gl16(nb + sOff[j], bufA + j * 8192 + wave * 1024);
        }
    }

    // ---- store [16 rows x 32 cols] per wave ----
    #pragma unroll
    for (int ct2 = 0; ct2 < 2; ++ct2)
        #pragma unroll
        for (int r = 0; r < 4; ++r)
            out[(size_t)(wrow + lg * 4 + r) * ADIM + ct2 * 16 + l15] = act[ct2][r];
}

extern "C" void kernel_launch(void* const* d_in, const int* in_sizes, int n_in,
                              void* d_out, int out_size, void* d_ws, size_t ws_size,
                              hipStream_t stream) {
    const float* feat = (const float*)d_in[0];
    const float* Wg   = (const float*)d_in[1];
    const float* bg   = (const float*)d_in[2];
    const float* W1   = (const float*)d_in[3];
    const float* b1   = (const float*)d_in[4];
    const float* W2   = (const float*)d_in[5];
    const float* b2   = (const float*)d_in[6];
    float* out = (float*)d_out;
    ushort* ws = (ushort*)d_ws;

    moe_prep<<<84, 256, 0, stream>>>(Wg, W1, W2, ws);
    const int nblk = 131072 / BM;   // 1024
    moe_main<<<nblk, NTHR, 0, stream>>>(feat, bg, b1, b2, ws, out);
}

// Round 7
// 575.045 us; speedup vs baseline: 1.4684x; 1.2079x over previous
//
#include <hip/hip_runtime.h>
#include <hip/hip_bf16.h>
#include <math.h>

#define FDIM 512
#define NEXP 4
#define HDIM 256
#define ADIM 32
#define BM   128
#define NTHR 512

typedef __attribute__((ext_vector_type(8))) short frag8;   // 8 bf16 (4 VGPR)
typedef __attribute__((ext_vector_type(4))) float f32x4;

// ws layout (ushort elements)
#define W1T_OFF 0                        // [4][256][512]  n-major (col stride 1KB)
#define W2T_OFF (4*256*512)              // [4][32][256]   a-major (col stride 512B)
#define WGT_OFF (W2T_OFF + 4*32*256)     // [16][512]      rows 4..15 zero

__device__ inline ushort f2bf(float x) {
    union { float f; unsigned u; } v; v.f = x;
    unsigned r = v.u + 0x7FFFu + ((v.u >> 16) & 1u);   // RNE
    return (ushort)(r >> 16);
}

__device__ inline frag8 pack8(f32x4 a, f32x4 b) {
    frag8 r;
    r[0] = (short)f2bf(a[0]); r[1] = (short)f2bf(a[1]);
    r[2] = (short)f2bf(a[2]); r[3] = (short)f2bf(a[3]);
    r[4] = (short)f2bf(b[0]); r[5] = (short)f2bf(b[1]);
    r[6] = (short)f2bf(b[2]); r[7] = (short)f2bf(b[3]);
    return r;
}

// async global->LDS, 16B per lane; LDS dest = wave-uniform base + lane*16
__device__ __forceinline__ void gl16(const void* g, void* l) {
    __builtin_amdgcn_global_load_lds(
        (const __attribute__((address_space(1))) unsigned int*)g,
        (__attribute__((address_space(3))) unsigned int*)l, 16, 0, 0);
}

// ---------------- prep: fp32 weights -> transposed bf16 in ws ----------------
__global__ __launch_bounds__(256) void moe_prep(const float* __restrict__ Wg,
                                                const float* __restrict__ W1,
                                                const float* __restrict__ W2,
                                                ushort* __restrict__ ws) {
    const int b = blockIdx.x, t = threadIdx.x;
    if (b < 64) {
        #pragma unroll
        for (int it = 0; it < 4; ++it) {
            int oct = (b * 256 + t) + it * 16384;
            int n = oct & 255, k8 = (oct >> 8) & 63, e = oct >> 14;
            f32x4 v0, v1;
            #pragma unroll
            for (int j = 0; j < 4; ++j) v0[j] = W1[(e*512 + k8*8 + j)*256 + n];
            #pragma unroll
            for (int j = 0; j < 4; ++j) v1[j] = W1[(e*512 + k8*8 + 4 + j)*256 + n];
            *(frag8*)(ws + W1T_OFF + (e*HDIM + n)*FDIM + k8*8) = pack8(v0, v1);
        }
    } else if (b < 80) {
        int oct = (b - 64) * 256 + t;
        int a = oct & 31, n8 = (oct >> 5) & 31, e = oct >> 10;
        f32x4 v0, v1;
        #pragma unroll
        for (int j = 0; j < 4; ++j) v0[j] = W2[(e*HDIM + n8*8 + j)*ADIM + a];
        #pragma unroll
        for (int j = 0; j < 4; ++j) v1[j] = W2[(e*HDIM + n8*8 + 4 + j)*ADIM + a];
        *(frag8*)(ws + W2T_OFF + (e*ADIM + a)*HDIM + n8*8) = pack8(v0, v1);
    } else {
        int oct = (b - 80) * 256 + t;
        int k8 = oct & 63, c = oct >> 6;
        f32x4 v0 = {0,0,0,0}, v1 = {0,0,0,0};
        if (c < NEXP) {
            #pragma unroll
            for (int j = 0; j < 4; ++j) v0[j] = Wg[(k8*8 + j)*NEXP + c];
            #pragma unroll
            for (int j = 0; j < 4; ++j) v1[j] = Wg[(k8*8 + 4 + j)*NEXP + c];
        }
        *(frag8*)(ws + WGT_OFF + c*FDIM + k8*8) = pack8(v0, v1);
    }
}

// ---------------- main fused kernel (v4) ----------------
// R6 post-mortem fixes:
//  (1) spills (WRITE_SIZE +61MB): col-half split -> acc1[8]; peak regs ~130 not ~170.
//  (2) pipeline order: issue(next granule) -> COMPUTE(cur) -> barrier  (v3 had
//      issue -> barrier -> compute, serializing full stage latency every chunk).
//  (3) W2 + Wg staged to LDS (no global loads inside any MFMA loop).
// LDS: buf0 32K | buf1 32K | w2b 16K | hbuf 64K | wgate 2K = 149504 B, 1 blk/CU.
__global__ __launch_bounds__(NTHR, 2) void moe_main(
        const float* __restrict__ feat, const float* __restrict__ bg,
        const float* __restrict__ b1,  const float* __restrict__ b2,
        const ushort* __restrict__ ws, float* __restrict__ out) {
    __shared__ __attribute__((aligned(16))) unsigned char smem[149504];
    unsigned char* buf0 = smem;                     // 32KB granule buffer (even)
    unsigned char* buf1 = smem + 32768;             // 32KB granule buffer (odd) / Wgt at gate time
    unsigned char* w2b  = smem + 65536;             // 16KB current expert W2
    unsigned char* hbuf = smem + 81920;             // 64KB H (8KB per wave)
    float*         wgate = (float*)(smem + 147456); // 8 waves x 16 rows x 4

    const int tid = threadIdx.x;
    const int lane = tid & 63;
    const int wave = tid >> 6;        // 0..7
    const int l15 = lane & 15;
    const int lg  = lane >> 4;        // 0..3
    const int row0 = blockIdx.x * BM;
    const int wrow = row0 + wave * 16;
    const char* w1b = (const char*)(ws + W1T_OFF);
    const char* w2g = (const char*)(ws + W2T_OFF);
    const char* wgb = (const char*)(ws + WGT_OFF);

    // per-thread inverse-swizzled staging source offsets (rule 21: linear LDS dest,
    // pre-swizzled global source, swizzled ds_read)
    int thrOff[4], w2Off[2], gOff[2];
    #pragma unroll
    for (int j = 0; j < 4; ++j) {                  // 32KB granule: [128 col][256B]
        int slot = j * 512 + tid, cl = slot >> 4;
        thrOff[j] = cl * 1024 + (((slot & 15) * 16) ^ ((cl & 7) << 4));
    }
    #pragma unroll
    for (int j = 0; j < 2; ++j) {                  // 16KB W2: [32 col][512B]
        int slot = j * 512 + tid, c2 = slot >> 5;
        w2Off[j] = c2 * 512 + (((slot & 31) * 16) ^ ((c2 & 7) << 4));
        int cg = slot >> 6;                        // 16KB Wgt: [16 col][1024B]
        gOff[j] = cg * 1024 + (((slot & 63) * 16) ^ ((cg & 7) << 4));
    }

    // prologue: stage Wgt -> buf1, granule0 -> buf0 (drained at first barrier)
    #pragma unroll
    for (int j = 0; j < 2; ++j) gl16(wgb + gOff[j], buf1 + j * 8192 + wave * 1024);
    #pragma unroll
    for (int j = 0; j < 4; ++j) gl16(w1b + thrOff[j], buf0 + j * 8192 + wave * 1024);

    // features -> A-fragments (16 rows per wave, K=512, read HBM once)
    frag8 afrag[16];
    {
        const float* fp = feat + (size_t)(wrow + l15) * FDIM + lg * 8;
        #pragma unroll
        for (int g4 = 0; g4 < 4; ++g4) {
            f32x4 t0[4], t1[4];
            #pragma unroll
            for (int s = 0; s < 4; ++s) {
                const float* p = fp + (g4 * 4 + s) * 32;
                t0[s] = *(const f32x4*)p;
                t1[s] = *(const f32x4*)(p + 4);
            }
            #pragma unroll
            for (int s = 0; s < 4; ++s) afrag[g4 * 4 + s] = pack8(t0[s], t1[s]);
        }
    }

    __syncthreads();   // Wgt + granule0 resident

    // ---- gate (reads buf1) + 4-lane-group softmax -> wgate ----
    {
        f32x4 ga = {0.f, 0.f, 0.f, 0.f};
        #pragma unroll
        for (int s = 0; s < 16; ++s) {
            frag8 bb = *(const frag8*)(buf1 + l15 * 1024 + ((s * 64 + lg * 16) ^ ((l15 & 7) << 4)));
            ga = __builtin_amdgcn_mfma_f32_16x16x32_bf16(afrag[s], bb, ga, 0, 0, 0);
        }
        float bgv = bg[l15 & 3];
        #pragma unroll
        for (int r = 0; r < 4; ++r) {
            float v = ga[r] + bgv;
            float m = fmaxf(v, __shfl_xor(v, 1));
            m = fmaxf(m, __shfl_xor(m, 2));
            float eV = expf(v - m);
            float sV = eV + __shfl_xor(eV, 1);
            sV += __shfl_xor(sV, 2);
            if (l15 < NEXP) wgate[wave * 64 + (lg * 4 + r) * 4 + l15] = eV / sV;
        }
    }
    __syncthreads();   // all waves done reading buf1 -> granule1 may target it

    f32x4 act[2];
    act[0] = (f32x4){0.f, 0.f, 0.f, 0.f};
    act[1] = (f32x4){0.f, 0.f, 0.f, 0.f};

    for (int e = 0; e < NEXP; ++e) {
        #pragma unroll
        for (int h = 0; h < 2; ++h) {              // col-half of HDIM
            f32x4 acc1[8];
            #pragma unroll
            for (int ct = 0; ct < 8; ++ct) acc1[ct] = (f32x4){0.f, 0.f, 0.f, 0.f};

            #pragma unroll
            for (int c = 0; c < 4; ++c) {          // K-chunks of 128
                const int g = e * 8 + h * 4 + c;   // granule id, parity = c&1
                // (2): issue next granule BEFORE compute
                if (g < 31) {
                    const int gn = g + 1;
                    const char* sb = w1b + (gn >> 2) * 131072 + (gn & 3) * 256;
                    unsigned char* db = (c & 1) ? buf0 : buf1;
                    #pragma unroll
                    for (int j = 0; j < 4; ++j)
                        gl16(sb + thrOff[j], db + j * 8192 + wave * 1024);
                }
                if (h == 0 && c == 1) {            // stage W2[e]; safe: after barrier
                    const char* sb2 = w2g + e * 16384;   // that proves GEMM2(e-1) done
                    #pragma unroll
                    for (int j = 0; j < 2; ++j)
                        gl16(sb2 + w2Off[j], w2b + j * 8192 + wave * 1024);
                }
                // compute granule g (32 ds_read_b128 + 32 MFMA covers stage latency)
                const unsigned char* src = (c & 1) ? buf1 : buf0;
                #pragma unroll
                for (int s = 0; s < 4; ++s) {
                    #pragma unroll
                    for (int ct = 0; ct < 8; ++ct) {
                        frag8 bb = *(const frag8*)(src + (ct * 16 + l15) * 256 +
                                                   ((s * 64 + lg * 16) ^ ((l15 & 7) << 4)));
                        acc1[ct] = __builtin_amdgcn_mfma_f32_16x16x32_bf16(
                            afrag[c * 4 + s], bb, acc1[ct], 0, 0, 0);
                    }
                }
                __syncthreads();                   // drains next granule's loads too
            }

            // H half -> per-wave LDS region (swizzled)
            unsigned char* hb = hbuf + wave * 8192;
            #pragma unroll
            for (int ct = 0; ct < 8; ++ct) {
                int col = h * 128 + ct * 16 + l15;
                float b1v = b1[e * HDIM + col];
                #pragma unroll
                for (int r = 0; r < 4; ++r) {
                    int row = lg * 4 + r;
                    float v = fmaxf(acc1[ct][r] + b1v, 0.f);
                    *(ushort*)(hb + row * 512 + ((col * 2) ^ ((row & 7) << 4))) = f2bf(v);
                }
            }
        }

        asm volatile("s_waitcnt lgkmcnt(0)" ::: "memory");   // own H writes visible
        __builtin_amdgcn_sched_barrier(0);                   // rule 18

        // ---- GEMM2: H[16x256] x W2t[e] from LDS, gate-weighted accumulate ----
        {
            f32x4 acc2[2];
            acc2[0] = (f32x4){0.f, 0.f, 0.f, 0.f};
            acc2[1] = (f32x4){0.f, 0.f, 0.f, 0.f};
            const unsigned char* hb = hbuf + wave * 8192;
            #pragma unroll
            for (int s2 = 0; s2 < 8; ++s2) {
                frag8 ha = *(const frag8*)(hb + l15 * 512 + ((s2 * 64 + lg * 16) ^ ((l15 & 7) << 4)));
                #pragma unroll
                for (int ct2 = 0; ct2 < 2; ++ct2) {
                    frag8 bb = *(const frag8*)(w2b + (ct2 * 16 + l15) * 512 +
                                               ((s2 * 64 + lg * 16) ^ ((l15 & 7) << 4)));
                    acc2[ct2] = __builtin_amdgcn_mfma_f32_16x16x32_bf16(ha, bb, acc2[ct2], 0, 0, 0);
                }
            }
            #pragma unroll
            for (int ct2 = 0; ct2 < 2; ++ct2) {
                float b2v = b2[e * ADIM + ct2 * 16 + l15];
                #pragma unroll
                for (int r = 0; r < 4; ++r) {
                    float gt = wgate[wave * 64 + (lg * 4 + r) * 4 + e];
                    act[ct2][r] += gt * (acc2[ct2][r] + b2v);
                }
            }
        }
    }

    // ---- store [16 rows x 32 cols] per wave ----
    #pragma unroll
    for (int ct2 = 0; ct2 < 2; ++ct2)
        #pragma unroll
        for (int r = 0; r < 4; ++r)
            out[(size_t)(wrow + lg * 4 + r) * ADIM + ct2 * 16 + l15] = act[ct2][r];
}

extern "C" void kernel_launch(void* const* d_in, const int* in_sizes, int n_in,
                              void* d_out, int out_size, void* d_ws, size_t ws_size,
                              hipStream_t stream) {
    const float* feat = (const float*)d_in[0];
    const float* Wg   = (const float*)d_in[1];
    const float* bg   = (const float*)d_in[2];
    const float* W1   = (const float*)d_in[3];
    const float* b1   = (const float*)d_in[4];
    const float* W2   = (const float*)d_in[5];
    const float* b2   = (const float*)d_in[6];
    float* out = (float*)d_out;
    ushort* ws = (ushort*)d_ws;

    moe_prep<<<84, 256, 0, stream>>>(Wg, W1, W2, ws);
    const int nblk = 131072 / BM;   // 1024
    moe_main<<<nblk, NTHR, 0, stream>>>(feat, bg, b1, b2, ws, out);
}